// Round 12
// baseline (254.843 us; speedup 1.0000x reference)
//
#include <hip/hip_runtime.h>
#include <float.h>
#include <math.h>

#define EPS 1e-5f
constexpr int B = 4, C = 3, N = 4096, E = 256;
constexpr int KNN = 15;            // 15 neighbors kept (top-16 minus rank 0)
constexpr int BN_ = B * N;         // 16384
constexpr int P = 8;               // points per block in fused kernel
constexpr int SR  = 264;           // hh_bf row stride (ushorts)
constexpr int SRF = 520;           // feat_bf row stride (ushorts)

typedef short bf8 __attribute__((ext_vector_type(8)));   // 8 bf16 in 4 VGPRs
typedef float f4  __attribute__((ext_vector_type(4)));

static __device__ __forceinline__ unsigned short f2bf(float f) {
    union { float f; unsigned int u; } v; v.f = f;
    unsigned int r = v.u + 0x7FFFu + ((v.u >> 16) & 1u);   // RTNE
    return (unsigned short)(r >> 16);
}
static __device__ __forceinline__ bf8 ld_bf8(const unsigned short* p) {
    return *(const bf8*)p;
}
// tanh-GELU: max |err| vs exact erf-gelu ~3e-4 (<< bf16 rounding).
static __device__ __forceinline__ float gelu_t(float v) {
    float z = v * fmaf(v * v, 0.07135482f, 1.59576912f);   // z = 2u
    float r = __builtin_amdgcn_rcpf(1.f + __expf(z));
    return fmaf(-v, r, v);
}

// ---------------- K2: bn1 (per-block redundant) + xn4 AoS + weights cvt + S9 zero ----------------
// blocks 0..63 : in-block BN1 reduction (deterministic, identical across blocks) then xn4
// block  64    : zeroes S9 (stream order: before knn's atomicAdds), then weight cvt
// blocks 64..159: tile-lane-major bf16 weights:
//   w2b_t: chunk (ft*8+kb)*64+lane = W2b[ft*16+(lane&15)][kb*32+(lane>>4)*8 ..+8] (ft-stride 4096)
//   wf_t : chunk (ot*16+kb)*64+lane = Wf[ot*16+(lane&15)][kb*32+(lane>>4)*8 ..+8] (ot-stride 8192)
__global__ void __launch_bounds__(256) compute_xn_cvt(
        const float* __restrict__ x,
        const float* __restrict__ g1, const float* __restrict__ b1,
        float4* __restrict__ xn4,
        const float* __restrict__ W2b, const float* __restrict__ Wf,
        unsigned short* __restrict__ w2b_t, unsigned short* __restrict__ wf_t,
        float* __restrict__ S9) {
    int blk = blockIdx.x;
    int t = threadIdx.x;
    if (blk < 64) {
        __shared__ float red[256][6];
        float s[3] = {0.f, 0.f, 0.f}, ss[3] = {0.f, 0.f, 0.f};
        #pragma unroll
        for (int c = 0; c < 3; c++) {
            for (int i4 = t; i4 < BN_ / 4; i4 += 256) {
                int b = i4 >> 10, n4 = i4 & 1023;
                float4 v = ((const float4*)(x + (b * C + c) * N))[n4];
                s[c]  += v.x + v.y + v.z + v.w;
                ss[c] += v.x * v.x + v.y * v.y + v.z * v.z + v.w * v.w;
            }
        }
        #pragma unroll
        for (int c = 0; c < 3; c++) { red[t][c] = s[c]; red[t][3 + c] = ss[c]; }
        __syncthreads();
        for (int w = 128; w > 0; w >>= 1) {
            if (t < w) {
                #pragma unroll
                for (int j = 0; j < 6; j++) red[t][j] += red[t + w][j];
            }
            __syncthreads();
        }
        float mu[3], rs[3];
        #pragma unroll
        for (int c = 0; c < 3; c++) {
            mu[c] = red[0][c] / (float)BN_;
            float var = red[0][3 + c] / (float)BN_ - mu[c] * mu[c];
            rs[c] = rsqrtf(var + EPS);
        }
        int i = blk * 256 + t;
        int b = i >> 12, n = i & (N - 1);
        float v[3];
        #pragma unroll
        for (int c = 0; c < C; c++)
            v[c] = (x[(b * C + c) * N + n] - mu[c]) * rs[c] * g1[c] + b1[c];
        float4 o; o.x = v[0]; o.y = v[1]; o.z = v[2];
        o.w = v[0] * v[0] + v[1] * v[1] + v[2] * v[2];
        xn4[i] = o;
        return;
    }
    if (blk == 64) {
        for (int j = t; j < 64 * 9; j += 256) S9[j] = 0.f;
    }
    int ch = (blk - 64) * 256 + t;     // chunk id (8 bf16 per chunk)
    if (ch < 8192) {                   // w2b: 65536 elems = 8192 chunks
        int lane = ch & 63, kb = (ch >> 6) & 7, ft16 = ch >> 9;
        int row = ft16 * 16 + (lane & 15);
        int col = kb * 32 + (lane >> 4) * 8;
        #pragma unroll
        for (int j = 0; j < 8; j++)
            w2b_t[ch * 8 + j] = f2bf(W2b[row * 256 + col + j]);
    } else {                           // wf: 131072 elems = 16384 chunks
        int c2 = ch - 8192;
        int lane = c2 & 63, kb = (c2 >> 6) & 15, ot = c2 >> 10;
        int row = ot * 16 + (lane & 15);
        int col = kb * 32 + (lane >> 4) * 8;
        #pragma unroll
        for (int j = 0; j < 8; j++)
            wf_t[c2 * 8 + j] = f2bf(Wf[row * 512 + col + j]);
    }
}

// ---------------- K3: top-16 (largest d2), one WAVE per point, no barriers ----------------
__global__ void __launch_bounds__(256, 4) knn_kernel(const float4* __restrict__ xn4,
                                                     unsigned short* __restrict__ idxout,
                                                     float* __restrict__ S9) {
    __shared__ float smom[4][15][9];
    int w = threadIdx.x >> 6, lane = threadIdx.x & 63;
    int i = blockIdx.x * 4 + w;
    int b = i >> 12, n = i & (N - 1);
    const float4* xb = xn4 + b * N;
    float4 qv = xb[n];
    float d[64];
    #pragma unroll
    for (int s = 0; s < 64; s++) {
        float4 p = xb[s * 64 + lane];
        d[s] = qv.w + p.w - 2.f * (qv.x * p.x + qv.y * p.y + qv.z * p.z);
    }
    float cm[8];
    #pragma unroll
    for (int c = 0; c < 8; c++) {
        float v = d[c * 8];
        #pragma unroll
        for (int s = 1; s < 8; s++) v = fmaxf(v, d[c * 8 + s]);
        cm[c] = v;
    }
    float bv = cm[0];
    #pragma unroll
    for (int c = 1; c < 8; c++) bv = fmaxf(bv, cm[c]);

    int myj = 0;
    for (int r = 0; r < 16; r++) {
        float wv = bv;
        #pragma unroll
        for (int off = 32; off > 0; off >>= 1)
            wv = fmaxf(wv, __shfl_xor(wv, off));
        unsigned long long msk = __ballot(bv == wv);
        int wl = __ffsll(msk) - 1;
        int gi = 0;
        if (lane == wl) {
            int cstar = 0; bool got = false;
            #pragma unroll
            for (int c = 0; c < 8; c++) {
                bool h = !got && (cm[c] == bv);
                cstar = h ? c : cstar;
                got = got || h;
            }
            int slot = 0;
            #pragma unroll
            for (int c = 0; c < 8; c++) {
                if (c == cstar) {   // 7 of 8 bodies skipped via execz
                    bool g2 = false;
                    #pragma unroll
                    for (int s = 0; s < 8; s++) {
                        bool h = !g2 && (d[c * 8 + s] == bv);
                        slot = h ? (c * 8 + s) : slot;
                        g2 = g2 || h;
                    }
                    #pragma unroll
                    for (int s = 0; s < 8; s++)
                        d[c * 8 + s] = (c * 8 + s == slot) ? -FLT_MAX : d[c * 8 + s];
                    float v = d[c * 8];
                    #pragma unroll
                    for (int s = 1; s < 8; s++) v = fmaxf(v, d[c * 8 + s]);
                    cm[c] = v;
                }
            }
            bv = cm[0];
            #pragma unroll
            for (int c = 1; c < 8; c++) bv = fmaxf(bv, cm[c]);
            gi = slot * 64 + lane;
        }
        int g = __shfl(gi, wl);
        if (lane == r - 1) myj = g;   // lanes 0..14 capture ranks 1..15
    }

    bool act = lane < 15;
    if (act) idxout[i * KNN + lane] = (unsigned short)myj;
    float4 pj = xb[act ? myj : n];
    float v0 = pj.x - qv.x, v1 = pj.y - qv.y, v2 = pj.z - qv.z;
    if (act) {
        float* mm = smom[w][lane];
        mm[0] = v0; mm[1] = v1; mm[2] = v2;
        mm[3] = v0 * v0; mm[4] = v1 * v1; mm[5] = v2 * v2;
        mm[6] = v0 * v1; mm[7] = v0 * v2; mm[8] = v1 * v2;
    }
    __syncthreads();
    int t = threadIdx.x;
    if (t < 36) {
        int wsel = t / 9, j = t % 9;
        float a = 0.f;
        #pragma unroll
        for (int u = 0; u < 15; u++) a += smom[wsel][u][j];
        atomicAdd(&S9[((blockIdx.x * 4 + wsel) & 63) * 9 + j], a);
    }
}

// ---------------- K6: fused [inline finalize] + W2a→BN2b→gelu→[MFMA W2b]→max | pe | [MFMA Wf] ----------------
// Inline finalize: wave 0 shfl-reduces S9; thread 0 derives alpha/beta/mu/Ehh (shared);
// every thread then computes its own e's (W2a*s, shift) in registers.
__global__ void __launch_bounds__(512, 4) fused_final(
        const float4* __restrict__ xn4, const unsigned short* __restrict__ idx,
        const float* __restrict__ S9,
        const float* __restrict__ g2a, const float* __restrict__ b2a,
        const float* __restrict__ W2a,
        const float* __restrict__ g2b, const float* __restrict__ b2b,
        const unsigned short* __restrict__ w2b_t,
        const float* __restrict__ W1, const float* __restrict__ bw1,
        const unsigned short* __restrict__ wf_t, const float* __restrict__ bfv,
        float* __restrict__ out) {
    __shared__ __align__(16) unsigned short hh_bf[128 * SR];   // row n=16p+k (p<8), col e
    __shared__ __align__(16) unsigned short feat_bf[8 * SRF];  // row p, col f 0..511
    __shared__ __align__(16) float4 hhat4[P][16];              // (h0,h1,h2,-) per (p,k)
    __shared__ float falpha[3], fbeta[3], fmu[3], fEhh[3][3];
    int i0 = blockIdx.x * P;
    int t = threadIdx.x;
    int b = i0 >> 12, n0 = i0 & (N - 1);
    const float4* xb = xn4 + b * N;
    const float cnt = (float)(BN_ * KNN);

    if (t < 64) {   // inline finalize, stage 1: reduce S9 within wave 0
        float v[9];
        #pragma unroll
        for (int j = 0; j < 9; j++) v[j] = S9[t * 9 + j];
        #pragma unroll
        for (int off = 32; off > 0; off >>= 1)
            #pragma unroll
            for (int j = 0; j < 9; j++) v[j] += __shfl_xor(v[j], off);
        if (t == 0) {
            float s2[3][3];
            s2[0][0] = v[3]; s2[1][1] = v[4]; s2[2][2] = v[5];
            s2[0][1] = s2[1][0] = v[6]; s2[0][2] = s2[2][0] = v[7]; s2[1][2] = s2[2][1] = v[8];
            float al[3], be[3], m[3];
            #pragma unroll
            for (int c = 0; c < 3; c++) {
                m[c] = v[c] / cnt;
                float var = s2[c][c] / cnt - m[c] * m[c];
                al[c] = g2a[c] * rsqrtf(var + EPS);
                be[c] = b2a[c] - m[c] * al[c];
                falpha[c] = al[c]; fbeta[c] = be[c]; fmu[c] = m[c];
            }
            #pragma unroll
            for (int c = 0; c < 3; c++)
                #pragma unroll
                for (int cc = 0; cc < 3; cc++)
                    fEhh[c][cc] = al[c] * al[cc] * (s2[c][cc] / cnt)
                                + al[c] * be[cc] * m[c] + be[c] * al[cc] * m[cc] + be[c] * be[cc];
        }
    }
    __syncthreads();

    // per-thread BN2b fold: w4 = (W2a*s, shift) for e = t&255 (registers, no LDS)
    float4 w4;
    {
        int e = t & 255;
        float wv0 = W2a[e * 3], wv1 = W2a[e * 3 + 1], wv2 = W2a[e * 3 + 2];
        float Eh0 = falpha[0] * fmu[0] + fbeta[0];
        float Eh1 = falpha[1] * fmu[1] + fbeta[1];
        float Eh2 = falpha[2] * fmu[2] + fbeta[2];
        float mean = wv0 * Eh0 + wv1 * Eh1 + wv2 * Eh2;
        float m2 = wv0 * (wv0 * fEhh[0][0] + wv1 * fEhh[0][1] + wv2 * fEhh[0][2])
                 + wv1 * (wv0 * fEhh[1][0] + wv1 * fEhh[1][1] + wv2 * fEhh[1][2])
                 + wv2 * (wv0 * fEhh[2][0] + wv1 * fEhh[2][1] + wv2 * fEhh[2][2]);
        float var = m2 - mean * mean;
        float s = g2b[e] * rsqrtf(var + EPS);
        w4.x = wv0 * s; w4.y = wv1 * s; w4.z = wv2 * s; w4.w = b2b[e] - mean * s;
    }

    if (t < P * KNN) {   // phase A: gather + BN2a affine (120 threads)
        int p = t / KNN, k = t % KNN;
        int j = idx[(i0 + p) * KNN + k];
        float4 pj = xb[j];
        float4 pn = xb[n0 + p];
        float4 h;
        h.x = falpha[0] * (pj.x - pn.x) + fbeta[0];
        h.y = falpha[1] * (pj.y - pn.y) + fbeta[1];
        h.z = falpha[2] * (pj.z - pn.z) + fbeta[2];
        h.w = 0.f;
        hhat4[p][k] = h;
    }
    __syncthreads();

    {   // phase B: h = w4 . hhat + shift, tanh-gelu (bf16 to LDS); point_emb
        int e = t & 255;
        int ph = t >> 8;             // half: points 4*ph .. 4*ph+3
        #pragma unroll
        for (int pp = 0; pp < 4; pp++) {
            int p = ph * 4 + pp;
            float g0 = 0.f;
            #pragma unroll
            for (int k = 0; k < KNN; k++) {
                float4 hv = hhat4[p][k];
                float v = fmaf(w4.x, hv.x, fmaf(w4.y, hv.y, fmaf(w4.z, hv.z, w4.w)));
                float g = gelu_t(v);
                hh_bf[(16 * p + k) * SR + e] = f2bf(g);
                if (k == 0) g0 = g;
            }
            hh_bf[(16 * p + 15) * SR + e] = f2bf(g0);   // dup row: max unaffected
            float4 pv = xb[n0 + p];
            feat_bf[p * SRF + e] = f2bf(bw1[e] + W1[e * 3] * pv.x
                       + W1[e * 3 + 1] * pv.y + W1[e * 3 + 2] * pv.z);
        }
    }
    __syncthreads();

    int w = t >> 6, lane = t & 63;
    int m = lane & 15, q = lane >> 4;

    {   // phase C: wave w -> f-tiles {2w, 2w+1}, all 8 points via 4 point-pairs
        #pragma unroll
        for (int f = 0; f < 2; f++) {
            int ft = w * 2 + f;
            bf8 a[8];
            #pragma unroll
            for (int kb = 0; kb < 8; kb++)
                a[kb] = ld_bf8(w2b_t + ft * 4096 + kb * 512 + lane * 8);
            #pragma unroll 1
            for (int pr = 0; pr < 4; pr++) {
                bf8 hfr[2][8];
                #pragma unroll
                for (int pi = 0; pi < 2; pi++)
                    #pragma unroll
                    for (int kb = 0; kb < 8; kb++)
                        hfr[pi][kb] = ld_bf8(&hh_bf[(16 * (pr * 2 + pi) + m) * SR + kb * 32 + q * 8]);
                #pragma unroll
                for (int pi = 0; pi < 2; pi++) {
                    f4 acc = {0.f, 0.f, 0.f, 0.f};
                    #pragma unroll
                    for (int kb = 0; kb < 8; kb++)
                        acc = __builtin_amdgcn_mfma_f32_16x16x32_bf16(hfr[pi][kb], a[kb], acc, 0, 0, 0);
                    float mx = fmaxf(fmaxf(acc[0], acc[1]), fmaxf(acc[2], acc[3]));
                    mx = fmaxf(mx, __shfl_xor(mx, 16));
                    mx = fmaxf(mx, __shfl_xor(mx, 32));
                    if (lane < 16)
                        feat_bf[(pr * 2 + pi) * SRF + E + ft * 16 + lane] = f2bf(mx);
                }
            }
        }
    }
    __syncthreads();

    {   // phase D: wave w -> o-tiles {2w, 2w+1}; cols = 8 points (m&7)
        bf8 fb[16];
        #pragma unroll
        for (int kb = 0; kb < 16; kb++)
            fb[kb] = ld_bf8(&feat_bf[(m & 7) * SRF + kb * 32 + q * 8]);
        #pragma unroll
        for (int o2 = 0; o2 < 2; o2++) {
            int ot = w * 2 + o2;
            f4 acc = {0.f, 0.f, 0.f, 0.f};
            #pragma unroll
            for (int kb = 0; kb < 16; kb++) {
                bf8 a = ld_bf8(wf_t + ot * 8192 + kb * 512 + lane * 8);
                acc = __builtin_amdgcn_mfma_f32_16x16x32_bf16(a, fb[kb], acc, 0, 0, 0);
            }
            if (m < P) {   // col = m = point; row = ot*16 + 4q + reg
                int o0 = ot * 16 + 4 * q;
                out[(b * E + o0 + 0) * N + n0 + m] = acc[0] + bfv[o0 + 0];
                out[(b * E + o0 + 1) * N + n0 + m] = acc[1] + bfv[o0 + 1];
                out[(b * E + o0 + 2) * N + n0 + m] = acc[2] + bfv[o0 + 2];
                out[(b * E + o0 + 3) * N + n0 + m] = acc[3] + bfv[o0 + 3];
            }
        }
    }
}

extern "C" void kernel_launch(void* const* d_in, const int* in_sizes, int n_in,
                              void* d_out, int out_size, void* d_ws, size_t ws_size,
                              hipStream_t stream) {
    (void)in_sizes; (void)n_in; (void)out_size; (void)ws_size;
    const float* x   = (const float*)d_in[0];
    const float* g1  = (const float*)d_in[1];
    const float* b1  = (const float*)d_in[2];
    const float* W1  = (const float*)d_in[3];
    const float* bw1 = (const float*)d_in[4];
    const float* g2a = (const float*)d_in[5];
    const float* b2a = (const float*)d_in[6];
    const float* W2a = (const float*)d_in[7];
    const float* g2b = (const float*)d_in[8];
    const float* b2b = (const float*)d_in[9];
    const float* W2b = (const float*)d_in[10];
    const float* Wf  = (const float*)d_in[11];
    const float* bfv = (const float*)d_in[12];
    float* out = (float*)d_out;

    char* ws = (char*)d_ws;
    size_t off = 0;
    auto alloc = [&](size_t bytes) { size_t o = off; off = (off + bytes + 255) & ~(size_t)255; return o; };
    float4* xn4           = (float4*)(ws + alloc(sizeof(float4) * BN_));
    unsigned short* idx   = (unsigned short*)(ws + alloc(sizeof(unsigned short) * BN_ * KNN));
    float* S9             = (float*)(ws + alloc(sizeof(float) * 64 * 9));
    unsigned short* w2bt  = (unsigned short*)(ws + alloc(sizeof(unsigned short) * E * E));
    unsigned short* wft   = (unsigned short*)(ws + alloc(sizeof(unsigned short) * E * 2 * E));

    compute_xn_cvt<<<160, 256, 0, stream>>>(x, g1, b1, xn4, W2b, Wf, w2bt, wft, S9);
    knn_kernel<<<BN_ / 4, 256, 0, stream>>>(xn4, idx, S9);
    fused_final<<<BN_ / P, 512, 0, stream>>>(xn4, idx, S9, g2a, b2a, W2a, g2b, b2b,
                                             w2bt, W1, bw1, wft, bfv, out);
}